// Round 8
// baseline (1435.042 us; speedup 1.0000x reference)
//
#include <hip/hip_runtime.h>
#include <hip/hip_bf16.h>

#define IN_CH 128
#define OUT_CH 256
#define BLK_SCAN 1024
#define BUCKET_SHIFT 4       // 16 nodes per bucket
#define BNODES 16

typedef __bf16 bf16x8 __attribute__((ext_vector_type(8)));
typedef float f32x4 __attribute__((ext_vector_type(4)));

__device__ inline unsigned short f2bf(float f) {
  union { float f; unsigned int u; } v; v.f = f;
  unsigned int u = v.u;
  u += 0x7FFFu + ((u >> 16) & 1u);   // round-to-nearest-even
  return (unsigned short)(u >> 16);
}

// Bpack element layout (ushort): idx = (((tn*4+ks)*4+kb)*16 + c)*8 + j
//   value = bf16( W[tn*16+c][ks*32 + kb*8 + j] )
// Same (kb,j)->k convention as A-fragments -> k-permutation cancels.
__device__ inline void build_bpack_elem(const float* __restrict__ W,
                                        unsigned short* __restrict__ Bpack, int i) {
  const int j  = i & 7;
  const int c  = (i >> 3) & 15;
  const int kb = (i >> 7) & 3;
  const int ks = (i >> 9) & 3;
  const int tn = i >> 11;
  Bpack[i] = f2bf(W[(size_t)(tn * 16 + c) * IN_CH + ks * 32 + kb * 8 + j]);
}

// init: build Bpack + zero nzero ints of cnt
__global__ void initB_kernel(const float* __restrict__ W, unsigned short* __restrict__ Bpack,
                             int* __restrict__ cnt, int nzero) {
  int i = blockIdx.x * blockDim.x + threadIdx.x;
  if (i < nzero) cnt[i] = 0;
  if (i < IN_CH * OUT_CH) build_bpack_elem(W, Bpack, i);
}

// ---------- shared scan kernels ----------
__global__ __launch_bounds__(BLK_SCAN) void scan_block_kernel(
    const int* __restrict__ count, int N, int* __restrict__ excl, int* __restrict__ bsum) {
  __shared__ int wsum[16];
  const int tid = threadIdx.x;
  const int i = blockIdx.x * BLK_SCAN + tid;
  const int v = (i < N) ? count[i] : 0;
  int x = v;
#pragma unroll
  for (int d = 1; d < 64; d <<= 1) {
    int t = __shfl_up(x, d, 64);
    if ((tid & 63) >= d) x += t;
  }
  if ((tid & 63) == 63) wsum[tid >> 6] = x;
  __syncthreads();
  if (tid < 16) {
    int s = wsum[tid];
#pragma unroll
    for (int d = 1; d < 16; d <<= 1) {
      int t = __shfl_up(s, d, 16);
      if (tid >= d) s += t;
    }
    wsum[tid] = s;
  }
  __syncthreads();
  const int w = tid >> 6;
  const int prefix = (w == 0) ? 0 : wsum[w - 1];
  if (i < N) excl[i] = prefix + x - v;
  if (tid == BLK_SCAN - 1) bsum[blockIdx.x] = prefix + x;
}

__global__ void scan_bsum_kernel(int* __restrict__ bsum, int nb) {
  __shared__ int tmp[256];
  const int tid = threadIdx.x;
  int run = 0;
  for (int s = 0; s < nb; s += 256) {
    int v = (s + tid < nb) ? bsum[s + tid] : 0;
    tmp[tid] = v;
    __syncthreads();
    for (int d = 1; d < 256; d <<= 1) {
      int t = (tid >= d) ? tmp[tid - d] : 0;
      __syncthreads();
      tmp[tid] += t;
      __syncthreads();
    }
    if (s + tid < nb) bsum[s + tid] = run + tmp[tid] - v;
    run += tmp[255];
    __syncthreads();
  }
}

__global__ void add_offsets_kernel(int* __restrict__ excl, const int* __restrict__ bsum,
                                   int* __restrict__ cursor, int N) {
  int i = blockIdx.x * blockDim.x + threadIdx.x;
  if (i < N) {
    int o = excl[i] + bsum[i / BLK_SCAN];
    excl[i] = o;
    cursor[i] = o;
  }
}

// =========================================================================
// PRIMARY PATH: radix-partition by 16-node bucket, then fused agg+project
// =========================================================================

__global__ void hist_bucket_kernel(const int* __restrict__ col, int E, int* __restrict__ cnt) {
  int i = blockIdx.x * blockDim.x + threadIdx.x;
  int b = i * 4;
  if (b + 4 <= E) {
    const int4 c = *(const int4*)(col + b);
    atomicAdd(&cnt[c.x >> BUCKET_SHIFT], 1);
    atomicAdd(&cnt[c.y >> BUCKET_SHIFT], 1);
    atomicAdd(&cnt[c.z >> BUCKET_SHIFT], 1);
    atomicAdd(&cnt[c.w >> BUCKET_SHIFT], 1);
  } else {
    for (int j = b; j < E; ++j) atomicAdd(&cnt[col[j] >> BUCKET_SHIFT], 1);
  }
}

// Stream te in edge order (sequential read) -> scatter rows into bucket
// append buffers as bf16 (256B rows, each owning 2 full 128B lines; K
// sequential write streams -> full write-back line efficiency).
// Lane l packs channels (l, l+64) -> one uint; phase2 unpacks the same way
// (chosen so the LDS ds_add pattern is 2-way bank aliasing = free).
__global__ __launch_bounds__(256) void bin_kernel(
    const float* __restrict__ te, const int* __restrict__ col,
    int* __restrict__ cursor, unsigned int* __restrict__ binned,
    int* __restrict__ bnid, int E) {
  const int lane = threadIdx.x & 63;
  const int gw = (blockIdx.x * 256 + threadIdx.x) >> 6;
  const int nw = (gridDim.x * 256) >> 6;
  for (int base = gw * 4; base < E; base += nw * 4) {
    int ne = E - base; if (ne > 4) ne = 4;
    int mypos = 0;
    if (lane < ne) {
      const int c = col[base + lane];
      mypos = atomicAdd(&cursor[c >> BUCKET_SHIFT], 1);
      bnid[mypos] = c & (BNODES - 1);
    }
#pragma unroll
    for (int j = 0; j < 4; ++j) {
      if (j < ne) {
        const int pos = __builtin_amdgcn_readlane(mypos, j);
        const float lo = te[(size_t)(base + j) * IN_CH + lane];
        const float hi = te[(size_t)(base + j) * IN_CH + lane + 64];
        binned[(size_t)pos * 64 + lane] =
            (unsigned int)f2bf(lo) | ((unsigned int)f2bf(hi) << 16);
      }
    }
  }
}

// One block per bucket: sequential read of the bucket's rows, ds_add_f32
// accumulate into an 8KB LDS tile, then fused MFMA projection -> out.
// C/D layout: col=lane&15, row=(lane>>4)*4+reg  [HW-verified]
__global__ __launch_bounds__(256) void phase2_kernel(
    const unsigned int* __restrict__ binned, const int* __restrict__ bnid,
    const int* __restrict__ start, const int* __restrict__ cend,
    const unsigned short* __restrict__ Bpack, const float* __restrict__ bias,
    float* __restrict__ out, int N) {
  __shared__ float agg[BNODES][IN_CH];   // 8 KB
  const int tid = threadIdx.x;
  const int wave = tid >> 6;
  const int lane = tid & 63;
  const int b = blockIdx.x;
  const int s = start[b];
  const int e = cend[b];

#pragma unroll
  for (int i = tid; i < BNODES * IN_CH; i += 256) ((float*)agg)[i] = 0.f;
  __syncthreads();

  for (int r0 = s + wave * 4; r0 < e; r0 += 16) {
    int nr = e - r0; if (nr > 4) nr = 4;
    unsigned int v[4]; int nid[4];
#pragma unroll
    for (int j = 0; j < 4; ++j) {
      if (j < nr) {
        v[j] = binned[(size_t)(r0 + j) * 64 + lane];
        nid[j] = bnid[r0 + j];
      }
    }
#pragma unroll
    for (int j = 0; j < 4; ++j) {
      if (j < nr) {
        union { unsigned int u; float f; } lo, hi;
        lo.u = v[j] << 16;
        hi.u = v[j] & 0xFFFF0000u;
        atomicAdd(&agg[nid[j]][lane], lo.f);        // ds_add_f32, 2-way bank = free
        atomicAdd(&agg[nid[j]][lane + 64], hi.f);
      }
    }
  }
  __syncthreads();

  // ---- fused MFMA projection for nodes [b*16, b*16+16) ----
  const int r  = lane & 15;
  const int kb = lane >> 4;
  const int m0 = b * BNODES;

  bf16x8 a[4];
#pragma unroll
  for (int ks = 0; ks < 4; ++ks) {
    bf16x8 t;
#pragma unroll
    for (int j = 0; j < 8; ++j) t[j] = (__bf16)agg[r][ks * 32 + kb * 8 + j];
    a[ks] = t;
  }

  f32x4 acc[4];
#pragma unroll
  for (int ct = 0; ct < 4; ++ct) acc[ct] = (f32x4){0.f, 0.f, 0.f, 0.f};

#pragma unroll
  for (int ct = 0; ct < 4; ++ct) {
    const int tn = wave * 4 + ct;
#pragma unroll
    for (int ks = 0; ks < 4; ++ks) {
      const bf16x8 bb = *(const bf16x8*)(Bpack + (size_t)((((tn * 4 + ks) * 4 + kb) * 16 + r) * 8));
      acc[ct] = __builtin_amdgcn_mfma_f32_16x16x32_bf16(a[ks], bb, acc[ct], 0, 0, 0);
    }
  }

#pragma unroll
  for (int ct = 0; ct < 4; ++ct) {
    const int colo = wave * 64 + ct * 16 + r;
    const float bv = bias[colo];
#pragma unroll
    for (int j = 0; j < 4; ++j) {
      const int m = m0 + kb * 4 + j;
      if (m < N) out[(size_t)m * OUT_CH + colo] = acc[ct][j] + bv;
    }
  }
}

// =========================================================================
// FALLBACK PATH (round-6 pipeline) — used when ws_size < primary need
// =========================================================================

__global__ void fb_hist_kernel(const int* __restrict__ col, int E, int* __restrict__ count) {
  int i = blockIdx.x * blockDim.x + threadIdx.x;
  int b = i * 4;
  if (b + 4 <= E) {
    const int4 c = *(const int4*)(col + b);
    atomicAdd(&count[c.x], 1);
    atomicAdd(&count[c.y], 1);
    atomicAdd(&count[c.z], 1);
    atomicAdd(&count[c.w], 1);
  } else {
    for (int j = b; j < E; ++j) atomicAdd(&count[col[j]], 1);
  }
}

__global__ void fb_scatter_kernel(const int* __restrict__ col, int E,
                                  int* __restrict__ cursor, int* __restrict__ sorted) {
  int i = blockIdx.x * blockDim.x + threadIdx.x;
  int b = i * 4;
  if (b + 4 <= E) {
    const int4 c = *(const int4*)(col + b);
    int p0 = atomicAdd(&cursor[c.x], 1); sorted[p0] = b;
    int p1 = atomicAdd(&cursor[c.y], 1); sorted[p1] = b + 1;
    int p2 = atomicAdd(&cursor[c.z], 1); sorted[p2] = b + 2;
    int p3 = atomicAdd(&cursor[c.w], 1); sorted[p3] = b + 3;
  } else {
    for (int j = b; j < E; ++j) {
      int pos = atomicAdd(&cursor[col[j]], 1);
      sorted[pos] = j;
    }
  }
}

__global__ __launch_bounds__(256) void fb_aggregate_kernel(
    const float* __restrict__ te, const int* __restrict__ offsets,
    const int* __restrict__ cend, const int* __restrict__ sorted,
    unsigned int* __restrict__ aggb32, int N) {
  const int g    = threadIdx.x >> 6;
  const int lane = threadIdx.x & 63;
  const int n = blockIdx.x * 4 + g;
  if (n >= N) return;

  float ax = 0.f, ay = 0.f;
  const int s = offsets[n];
  const int e = cend[n];
  const size_t co = (size_t)(lane * 2);
  if (s < e) {
    int my = 0;
    if (lane < 16) {
      int idx = s + lane;
      my = sorted[idx < e ? idx : (e - 1)];
    }
    for (int i = s; i < e; i += 16) {
#define EID(j) __builtin_amdgcn_readlane(my, j)
      const float2 t0  = *(const float2*)(te + (size_t)EID(0)  * IN_CH + co);
      const float2 t1  = *(const float2*)(te + (size_t)EID(1)  * IN_CH + co);
      const float2 t2  = *(const float2*)(te + (size_t)EID(2)  * IN_CH + co);
      const float2 t3  = *(const float2*)(te + (size_t)EID(3)  * IN_CH + co);
      const float2 t4  = *(const float2*)(te + (size_t)EID(4)  * IN_CH + co);
      const float2 t5  = *(const float2*)(te + (size_t)EID(5)  * IN_CH + co);
      const float2 t6  = *(const float2*)(te + (size_t)EID(6)  * IN_CH + co);
      const float2 t7  = *(const float2*)(te + (size_t)EID(7)  * IN_CH + co);
      const float2 t8  = *(const float2*)(te + (size_t)EID(8)  * IN_CH + co);
      const float2 t9  = *(const float2*)(te + (size_t)EID(9)  * IN_CH + co);
      const float2 t10 = *(const float2*)(te + (size_t)EID(10) * IN_CH + co);
      const float2 t11 = *(const float2*)(te + (size_t)EID(11) * IN_CH + co);
      const float2 t12 = *(const float2*)(te + (size_t)EID(12) * IN_CH + co);
      const float2 t13 = *(const float2*)(te + (size_t)EID(13) * IN_CH + co);
      const float2 t14 = *(const float2*)(te + (size_t)EID(14) * IN_CH + co);
      const float2 t15 = *(const float2*)(te + (size_t)EID(15) * IN_CH + co);
#undef EID
      int nxt = 0;
      {
        const int ib = i + 16;
        if (lane < 16 && ib < e) {
          int idx = ib + lane;
          nxt = sorted[idx < e ? idx : (e - 1)];
        }
      }
      const int rem = e - i;
      if (rem >= 16) {
        ax += (t0.x + t1.x) + (t2.x + t3.x) + (t4.x + t5.x) + (t6.x + t7.x) +
              (t8.x + t9.x) + (t10.x + t11.x) + (t12.x + t13.x) + (t14.x + t15.x);
        ay += (t0.y + t1.y) + (t2.y + t3.y) + (t4.y + t5.y) + (t6.y + t7.y) +
              (t8.y + t9.y) + (t10.y + t11.y) + (t12.y + t13.y) + (t14.y + t15.y);
      } else {
        ax += t0.x; ay += t0.y;
#define ACC(j, tj) { const float c = (rem > j) ? 1.f : 0.f; \
                     ax = fmaf(c, tj.x, ax); ay = fmaf(c, tj.y, ay); }
        ACC(1, t1)  ACC(2, t2)  ACC(3, t3)  ACC(4, t4)  ACC(5, t5)
        ACC(6, t6)  ACC(7, t7)  ACC(8, t8)  ACC(9, t9)  ACC(10, t10)
        ACC(11, t11) ACC(12, t12) ACC(13, t13) ACC(14, t14) ACC(15, t15)
#undef ACC
      }
      my = nxt;
    }
  }
  aggb32[(size_t)n * 64 + lane] = (unsigned int)f2bf(ax) | ((unsigned int)f2bf(ay) << 16);
}

__global__ __launch_bounds__(256) void fb_project_mfma(
    const unsigned short* __restrict__ aggb, const unsigned short* __restrict__ Bpack,
    const float* __restrict__ bias, float* __restrict__ out, int N) {
  const int wave = threadIdx.x >> 6;
  const int lane = threadIdx.x & 63;
  const int r  = lane & 15;
  const int kb = lane >> 4;
  const int m0 = blockIdx.x * 16;
  const int rr = (m0 + r < N) ? (m0 + r) : (N - 1);

  bf16x8 a[4];
  const unsigned short* arow = aggb + (size_t)rr * IN_CH + kb * 8;
#pragma unroll
  for (int ks = 0; ks < 4; ++ks)
    a[ks] = *(const bf16x8*)(arow + ks * 32);

  f32x4 acc[4];
#pragma unroll
  for (int ct = 0; ct < 4; ++ct) acc[ct] = (f32x4){0.f, 0.f, 0.f, 0.f};

#pragma unroll
  for (int ct = 0; ct < 4; ++ct) {
    const int tn = wave * 4 + ct;
#pragma unroll
    for (int ks = 0; ks < 4; ++ks) {
      const bf16x8 bb = *(const bf16x8*)(Bpack + (size_t)((((tn * 4 + ks) * 4 + kb) * 16 + r) * 8));
      acc[ct] = __builtin_amdgcn_mfma_f32_16x16x32_bf16(a[ks], bb, acc[ct], 0, 0, 0);
    }
  }

#pragma unroll
  for (int ct = 0; ct < 4; ++ct) {
    const int colo = wave * 64 + ct * 16 + r;
    const float bv = bias[colo];
#pragma unroll
    for (int j = 0; j < 4; ++j) {
      const int m = m0 + kb * 4 + j;
      if (m < N) out[(size_t)m * OUT_CH + colo] = acc[ct][j] + bv;
    }
  }
}

// =========================================================================

extern "C" void kernel_launch(void* const* d_in, const int* in_sizes, int n_in,
                              void* d_out, int out_size, void* d_ws, size_t ws_size,
                              hipStream_t stream) {
  const int* edge_index = (const int*)d_in[0];
  const float* te       = (const float*)d_in[1];
  const float* W        = (const float*)d_in[3];
  const float* bias     = (const float*)d_in[4];
  float* out            = (float*)d_out;

  const int E = in_sizes[0] / 2;
  const int N = out_size / OUT_CH;
  const int* col = edge_index + E;  // edge_index[1]

  const int K = (N + BNODES - 1) >> BUCKET_SHIFT;   // buckets of 16 nodes
  const int Kp = (K + 3) & ~3;
  const int Ep = (E + 3) & ~3;

  // ---- primary layout ----
  char* p = (char*)d_ws;
  unsigned short* Bpack = (unsigned short*)p;      p += 65536;
  int* cnt    = (int*)p;                           p += (size_t)Kp * 4;
  int* start  = (int*)p;                           p += (size_t)Kp * 4;
  int* cursor = (int*)p;                           p += (size_t)Kp * 4;
  int* bsum   = (int*)p;                           p += 4096 * 4;
  int* bnid   = (int*)p;                           p += (size_t)Ep * 4;
  p = (char*)(((uintptr_t)p + 255) & ~(uintptr_t)255);
  unsigned int* binned = (unsigned int*)p;         p += (size_t)E * 256;
  const size_t need_primary = (size_t)(p - (char*)d_ws);

  if (ws_size >= need_primary) {
    const int nb = (K + BLK_SCAN - 1) / BLK_SCAN;
    const int init_n = (K > IN_CH * OUT_CH) ? K : IN_CH * OUT_CH;
    hipLaunchKernelGGL(initB_kernel, dim3((init_n + 255) / 256), dim3(256), 0, stream,
                       W, Bpack, cnt, K);
    hipLaunchKernelGGL(hist_bucket_kernel, dim3((E / 4 + 255) / 256), dim3(256), 0, stream,
                       col, E, cnt);
    hipLaunchKernelGGL(scan_block_kernel, dim3(nb), dim3(BLK_SCAN), 0, stream,
                       cnt, K, start, bsum);
    hipLaunchKernelGGL(scan_bsum_kernel, dim3(1), dim3(256), 0, stream, bsum, nb);
    hipLaunchKernelGGL(add_offsets_kernel, dim3((K + 255) / 256), dim3(256), 0, stream,
                       start, bsum, cursor, K);
    hipLaunchKernelGGL(bin_kernel, dim3(2048), dim3(256), 0, stream,
                       te, col, cursor, binned, bnid, E);
    hipLaunchKernelGGL(phase2_kernel, dim3(K), dim3(256), 0, stream,
                       binned, bnid, start, cursor, Bpack, bias, out, N);
    return;
  }

  // ---- fallback: round-6 sorted-gather pipeline ----
  const int Np = (N + 3) & ~3;
  int* ws       = (int*)d_ws;
  int* fcount   = ws;
  int* foffsets = ws + Np;
  int* fcursor  = ws + 2 * Np;
  int* fbsum    = ws + 3 * Np;
  int* fsorted  = ws + 3 * Np + 4096;
  unsigned short* fBpack = (unsigned short*)(ws + 3 * Np + 4096 + Ep);
  unsigned int*   faggb  = (unsigned int*)(ws + 3 * Np + 4096 + Ep + 16384);

  const int nbf = (N + BLK_SCAN - 1) / BLK_SCAN;
  const int init_n = (N > IN_CH * OUT_CH) ? N : IN_CH * OUT_CH;

  hipLaunchKernelGGL(initB_kernel, dim3((init_n + 255) / 256), dim3(256), 0, stream,
                     W, fBpack, fcount, N);
  hipLaunchKernelGGL(fb_hist_kernel, dim3((E / 4 + 255) / 256), dim3(256), 0, stream,
                     col, E, fcount);
  hipLaunchKernelGGL(scan_block_kernel, dim3(nbf), dim3(BLK_SCAN), 0, stream,
                     fcount, N, foffsets, fbsum);
  hipLaunchKernelGGL(scan_bsum_kernel, dim3(1), dim3(256), 0, stream, fbsum, nbf);
  hipLaunchKernelGGL(add_offsets_kernel, dim3((N + 255) / 256), dim3(256), 0, stream,
                     foffsets, fbsum, fcursor, N);
  hipLaunchKernelGGL(fb_scatter_kernel, dim3((E / 4 + 255) / 256), dim3(256), 0, stream,
                     col, E, fcursor, fsorted);
  hipLaunchKernelGGL(fb_aggregate_kernel, dim3((N + 3) / 4), dim3(256), 0, stream,
                     te, foffsets, fcursor, fsorted, faggb, N);
  hipLaunchKernelGGL(fb_project_mfma, dim3((N + 15) / 16), dim3(256), 0, stream,
                     (const unsigned short*)faggb, fBpack, bias, out, N);
}

// Round 9
// 1406.859 us; speedup vs baseline: 1.0200x; 1.0200x over previous
//
#include <hip/hip_runtime.h>
#include <hip/hip_bf16.h>

#define IN_CH 128
#define OUT_CH 256
#define BLK_SCAN 1024
#define BUCKET_SHIFT 4       // 16 nodes per bucket
#define BNODES 16
#define AGG_STRIDE 132       // +4 pad: ds_add bank = (nid*4+ch)%32 -> 2-way (free)

typedef __bf16 bf16x8 __attribute__((ext_vector_type(8)));
typedef float f32x4 __attribute__((ext_vector_type(4)));

__device__ inline unsigned short f2bf(float f) {
  union { float f; unsigned int u; } v; v.f = f;
  unsigned int u = v.u;
  u += 0x7FFFu + ((u >> 16) & 1u);   // round-to-nearest-even
  return (unsigned short)(u >> 16);
}

// Bpack element layout (ushort): idx = (((tn*4+ks)*4+kb)*16 + c)*8 + j
//   value = bf16( W[tn*16+c][ks*32 + kb*8 + j] )
// Same (kb,j)->k convention as A-fragments -> k-permutation cancels.
__global__ void initB_kernel(const float* __restrict__ W, unsigned short* __restrict__ Bpack,
                             int* __restrict__ cnt, int nzero) {
  int i = blockIdx.x * blockDim.x + threadIdx.x;
  if (i < nzero) cnt[i] = 0;
  if (i < IN_CH * OUT_CH) {
    const int j  = i & 7;
    const int c  = (i >> 3) & 15;
    const int kb = (i >> 7) & 3;
    const int ks = (i >> 9) & 3;
    const int tn = i >> 11;
    Bpack[i] = f2bf(W[(size_t)(tn * 16 + c) * IN_CH + ks * 32 + kb * 8 + j]);
  }
}

// ---------- scan kernels ----------
__global__ __launch_bounds__(BLK_SCAN) void scan_block_kernel(
    const int* __restrict__ count, int N, int* __restrict__ excl, int* __restrict__ bsum) {
  __shared__ int wsum[16];
  const int tid = threadIdx.x;
  const int i = blockIdx.x * BLK_SCAN + tid;
  const int v = (i < N) ? count[i] : 0;
  int x = v;
#pragma unroll
  for (int d = 1; d < 64; d <<= 1) {
    int t = __shfl_up(x, d, 64);
    if ((tid & 63) >= d) x += t;
  }
  if ((tid & 63) == 63) wsum[tid >> 6] = x;
  __syncthreads();
  if (tid < 16) {
    int s = wsum[tid];
#pragma unroll
    for (int d = 1; d < 16; d <<= 1) {
      int t = __shfl_up(s, d, 16);
      if (tid >= d) s += t;
    }
    wsum[tid] = s;
  }
  __syncthreads();
  const int w = tid >> 6;
  const int prefix = (w == 0) ? 0 : wsum[w - 1];
  if (i < N) excl[i] = prefix + x - v;
  if (tid == BLK_SCAN - 1) bsum[blockIdx.x] = prefix + x;
}

__global__ void scan_bsum_kernel(int* __restrict__ bsum, int nb) {
  __shared__ int tmp[256];
  const int tid = threadIdx.x;
  int run = 0;
  for (int s = 0; s < nb; s += 256) {
    int v = (s + tid < nb) ? bsum[s + tid] : 0;
    tmp[tid] = v;
    __syncthreads();
    for (int d = 1; d < 256; d <<= 1) {
      int t = (tid >= d) ? tmp[tid - d] : 0;
      __syncthreads();
      tmp[tid] += t;
      __syncthreads();
    }
    if (s + tid < nb) bsum[s + tid] = run + tmp[tid] - v;
    run += tmp[255];
    __syncthreads();
  }
}

__global__ void add_offsets_kernel(int* __restrict__ excl, const int* __restrict__ bsum,
                                   int* __restrict__ cursor, int N) {
  int i = blockIdx.x * blockDim.x + threadIdx.x;
  if (i < N) {
    int o = excl[i] + bsum[i / BLK_SCAN];
    excl[i] = o;
    cursor[i] = o;
  }
}

__global__ void hist_bucket_kernel(const int* __restrict__ col, int E, int* __restrict__ cnt) {
  int i = blockIdx.x * blockDim.x + threadIdx.x;
  int b = i * 4;
  if (b + 4 <= E) {
    const int4 c = *(const int4*)(col + b);
    atomicAdd(&cnt[c.x >> BUCKET_SHIFT], 1);
    atomicAdd(&cnt[c.y >> BUCKET_SHIFT], 1);
    atomicAdd(&cnt[c.z >> BUCKET_SHIFT], 1);
    atomicAdd(&cnt[c.w >> BUCKET_SHIFT], 1);
  } else {
    for (int j = b; j < E; ++j) atomicAdd(&cnt[col[j] >> BUCKET_SHIFT], 1);
  }
}

// Stream te in edge order (sequential read) -> scatter bf16 rows (256B, two
// full 128B lines) into bucket append buffers. Lane l packs (l, l+64).
__global__ __launch_bounds__(256) void bin_kernel(
    const float* __restrict__ te, const int* __restrict__ col,
    int* __restrict__ cursor, unsigned int* __restrict__ binned,
    int* __restrict__ bnid, int E) {
  const int lane = threadIdx.x & 63;
  const int gw = (blockIdx.x * 256 + threadIdx.x) >> 6;
  const int nw = (gridDim.x * 256) >> 6;
  for (int base = gw * 4; base < E; base += nw * 4) {
    int ne = E - base; if (ne > 4) ne = 4;
    int mypos = 0;
    if (lane < ne) {
      const int c = col[base + lane];
      mypos = atomicAdd(&cursor[c >> BUCKET_SHIFT], 1);
      bnid[mypos] = c & (BNODES - 1);
    }
#pragma unroll
    for (int j = 0; j < 4; ++j) {
      if (j < ne) {
        const int pos = __builtin_amdgcn_readlane(mypos, j);
        const float lo = te[(size_t)(base + j) * IN_CH + lane];
        const float hi = te[(size_t)(base + j) * IN_CH + lane + 64];
        binned[(size_t)pos * 64 + lane] =
            (unsigned int)f2bf(lo) | ((unsigned int)f2bf(hi) << 16);
      }
    }
  }
}

// One block per bucket: sequential read of the bucket's rows, NATIVE ds_add_f32
// (unsafeAtomicAdd) into padded LDS tile, then fused MFMA projection.
// C/D layout: col=lane&15, row=(lane>>4)*4+reg  [HW-verified]
__global__ __launch_bounds__(256) void phase2_kernel(
    const unsigned int* __restrict__ binned, const int* __restrict__ bnid,
    const int* __restrict__ start, const int* __restrict__ cend,
    const unsigned short* __restrict__ Bpack, const float* __restrict__ bias,
    float* __restrict__ out, int N) {
  __shared__ float agg[BNODES][AGG_STRIDE];   // 8.25 KB
  const int tid = threadIdx.x;
  const int wave = tid >> 6;
  const int lane = tid & 63;
  const int b = blockIdx.x;
  const int s = start[b];
  const int e = cend[b];

  for (int i = tid; i < BNODES * AGG_STRIDE; i += 256) ((float*)agg)[i] = 0.f;
  __syncthreads();

  // 8 rows in flight per wave-iteration (2KB MLP per wave)
  for (int r0 = s + wave * 8; r0 < e; r0 += 32) {
    int nr = e - r0; if (nr > 8) nr = 8;
    unsigned int v[8]; int nid[8];
#pragma unroll
    for (int j = 0; j < 8; ++j) {
      if (j < nr) {
        v[j] = binned[(size_t)(r0 + j) * 64 + lane];
        nid[j] = bnid[r0 + j];
      }
    }
#pragma unroll
    for (int j = 0; j < 8; ++j) {
      if (j < nr) {
        union { unsigned int u; float f; } lo, hi;
        lo.u = v[j] << 16;
        hi.u = v[j] & 0xFFFF0000u;
        unsafeAtomicAdd(&agg[nid[j]][lane], lo.f);        // native ds_add_f32
        unsafeAtomicAdd(&agg[nid[j]][lane + 64], hi.f);
      }
    }
  }
  __syncthreads();

  // ---- fused MFMA projection for nodes [b*16, b*16+16) ----
  const int r  = lane & 15;
  const int kb = lane >> 4;
  const int m0 = b * BNODES;

  bf16x8 a[4];
#pragma unroll
  for (int ks = 0; ks < 4; ++ks) {
    bf16x8 t;
#pragma unroll
    for (int j = 0; j < 8; ++j) t[j] = (__bf16)agg[r][ks * 32 + kb * 8 + j];
    a[ks] = t;
  }

  f32x4 acc[4];
#pragma unroll
  for (int ct = 0; ct < 4; ++ct) acc[ct] = (f32x4){0.f, 0.f, 0.f, 0.f};

#pragma unroll
  for (int ct = 0; ct < 4; ++ct) {
    const int tn = wave * 4 + ct;
#pragma unroll
    for (int ks = 0; ks < 4; ++ks) {
      const bf16x8 bb = *(const bf16x8*)(Bpack + (size_t)((((tn * 4 + ks) * 4 + kb) * 16 + r) * 8));
      acc[ct] = __builtin_amdgcn_mfma_f32_16x16x32_bf16(a[ks], bb, acc[ct], 0, 0, 0);
    }
  }

#pragma unroll
  for (int ct = 0; ct < 4; ++ct) {
    const int colo = wave * 64 + ct * 16 + r;
    const float bv = bias[colo];
#pragma unroll
    for (int j = 0; j < 4; ++j) {
      const int m = m0 + kb * 4 + j;
      if (m < N) out[(size_t)m * OUT_CH + colo] = acc[ct][j] + bv;
    }
  }
}

extern "C" void kernel_launch(void* const* d_in, const int* in_sizes, int n_in,
                              void* d_out, int out_size, void* d_ws, size_t ws_size,
                              hipStream_t stream) {
  const int* edge_index = (const int*)d_in[0];
  const float* te       = (const float*)d_in[1];
  const float* W        = (const float*)d_in[3];
  const float* bias     = (const float*)d_in[4];
  float* out            = (float*)d_out;

  const int E = in_sizes[0] / 2;
  const int N = out_size / OUT_CH;
  const int* col = edge_index + E;  // edge_index[1]

  const int K = (N + BNODES - 1) >> BUCKET_SHIFT;   // buckets of 16 nodes
  const int Kp = (K + 3) & ~3;
  const int Ep = (E + 3) & ~3;

  char* p = (char*)d_ws;
  unsigned short* Bpack = (unsigned short*)p;      p += 65536;
  int* cnt    = (int*)p;                           p += (size_t)Kp * 4;
  int* start  = (int*)p;                           p += (size_t)Kp * 4;
  int* cursor = (int*)p;                           p += (size_t)Kp * 4;
  int* bsum   = (int*)p;                           p += 4096 * 4;
  int* bnid   = (int*)p;                           p += (size_t)Ep * 4;
  p = (char*)(((uintptr_t)p + 255) & ~(uintptr_t)255);
  unsigned int* binned = (unsigned int*)p;

  const int nb = (K + BLK_SCAN - 1) / BLK_SCAN;
  const int init_n = (K > IN_CH * OUT_CH) ? K : IN_CH * OUT_CH;

  hipLaunchKernelGGL(initB_kernel, dim3((init_n + 255) / 256), dim3(256), 0, stream,
                     W, Bpack, cnt, K);
  hipLaunchKernelGGL(hist_bucket_kernel, dim3((E / 4 + 255) / 256), dim3(256), 0, stream,
                     col, E, cnt);
  hipLaunchKernelGGL(scan_block_kernel, dim3(nb), dim3(BLK_SCAN), 0, stream,
                     cnt, K, start, bsum);
  hipLaunchKernelGGL(scan_bsum_kernel, dim3(1), dim3(256), 0, stream, bsum, nb);
  hipLaunchKernelGGL(add_offsets_kernel, dim3((K + 255) / 256), dim3(256), 0, stream,
                     start, bsum, cursor, K);
  hipLaunchKernelGGL(bin_kernel, dim3(2048), dim3(256), 0, stream,
                     te, col, cursor, binned, bnid, E);
  hipLaunchKernelGGL(phase2_kernel, dim3(K), dim3(256), 0, stream,
                     binned, bnid, start, cursor, Bpack, bias, out, N);
}

// Round 10
// 463.461 us; speedup vs baseline: 3.0964x; 3.0355x over previous
//
#include <hip/hip_runtime.h>
#include <hip/hip_bf16.h>

#define IN_CH 128
#define OUT_CH 256
#define BLK_SCAN 1024
#define AGG_STRIDE 132

typedef __bf16 bf16x8 __attribute__((ext_vector_type(8)));
typedef float f32x4 __attribute__((ext_vector_type(4)));

__device__ inline unsigned short f2bf(float f) {
  union { float f; unsigned int u; } v; v.f = f;
  unsigned int u = v.u;
  u += 0x7FFFu + ((u >> 16) & 1u);   // round-to-nearest-even
  return (unsigned short)(u >> 16);
}

__device__ inline float bfhi2f(unsigned int u) {   // high bf16 -> float
  union { unsigned int u; float f; } v; v.u = u & 0xFFFF0000u; return v.f;
}
__device__ inline float bflo2f(unsigned int u) {   // low bf16 -> float
  union { unsigned int u; float f; } v; v.u = u << 16; return v.f;
}

// Bpack element layout (ushort): idx = (((tn*4+ks)*4+kb)*16 + c)*8 + j
//   value = bf16( W[tn*16+c][ks*32 + kb*8 + j] )
// Same (kb,j)->k convention as A-fragments -> k-permutation cancels.
__global__ void initB_kernel(const float* __restrict__ W, unsigned short* __restrict__ Bpack,
                             int* __restrict__ cnt, int nzero) {
  int i = blockIdx.x * blockDim.x + threadIdx.x;
  if (i < nzero) cnt[i] = 0;
  if (i < IN_CH * OUT_CH) {
    const int j  = i & 7;
    const int c  = (i >> 3) & 15;
    const int kb = (i >> 7) & 3;
    const int ks = (i >> 9) & 3;
    const int tn = i >> 11;
    Bpack[i] = f2bf(W[(size_t)(tn * 16 + c) * IN_CH + ks * 32 + kb * 8 + j]);
  }
}

__global__ void hist_kernel(const int* __restrict__ col, int E, int* __restrict__ count) {
  int i = blockIdx.x * blockDim.x + threadIdx.x;
  int b = i * 4;
  if (b + 4 <= E) {
    const int4 c = *(const int4*)(col + b);
    atomicAdd(&count[c.x], 1);
    atomicAdd(&count[c.y], 1);
    atomicAdd(&count[c.z], 1);
    atomicAdd(&count[c.w], 1);
  } else {
    for (int j = b; j < E; ++j) atomicAdd(&count[col[j]], 1);
  }
}

// ---------- scan kernels ----------
__global__ __launch_bounds__(BLK_SCAN) void scan_block_kernel(
    const int* __restrict__ count, int N, int* __restrict__ excl, int* __restrict__ bsum) {
  __shared__ int wsum[16];
  const int tid = threadIdx.x;
  const int i = blockIdx.x * BLK_SCAN + tid;
  const int v = (i < N) ? count[i] : 0;
  int x = v;
#pragma unroll
  for (int d = 1; d < 64; d <<= 1) {
    int t = __shfl_up(x, d, 64);
    if ((tid & 63) >= d) x += t;
  }
  if ((tid & 63) == 63) wsum[tid >> 6] = x;
  __syncthreads();
  if (tid < 16) {
    int s = wsum[tid];
#pragma unroll
    for (int d = 1; d < 16; d <<= 1) {
      int t = __shfl_up(s, d, 16);
      if (tid >= d) s += t;
    }
    wsum[tid] = s;
  }
  __syncthreads();
  const int w = tid >> 6;
  const int prefix = (w == 0) ? 0 : wsum[w - 1];
  if (i < N) excl[i] = prefix + x - v;
  if (tid == BLK_SCAN - 1) bsum[blockIdx.x] = prefix + x;
}

__global__ void scan_bsum_kernel(int* __restrict__ bsum, int nb) {
  __shared__ int tmp[256];
  const int tid = threadIdx.x;
  int run = 0;
  for (int s = 0; s < nb; s += 256) {
    int v = (s + tid < nb) ? bsum[s + tid] : 0;
    tmp[tid] = v;
    __syncthreads();
    for (int d = 1; d < 256; d <<= 1) {
      int t = (tid >= d) ? tmp[tid - d] : 0;
      __syncthreads();
      tmp[tid] += t;
      __syncthreads();
    }
    if (s + tid < nb) bsum[s + tid] = run + tmp[tid] - v;
    run += tmp[255];
    __syncthreads();
  }
}

__global__ void add_offsets_kernel(int* __restrict__ excl, const int* __restrict__ bsum,
                                   int* __restrict__ cursor, int N) {
  int i = blockIdx.x * blockDim.x + threadIdx.x;
  if (i < N) {
    int o = excl[i] + bsum[i / BLK_SCAN];
    excl[i] = o;
    cursor[i] = o;
  }
}

// Stream te in edge order (sequential read) -> write bf16 rows (256B, two full
// 128B lines) into per-NODE contiguous slots. Lane l packs (l, l+64) -> uint.
__global__ __launch_bounds__(256) void bin_kernel(
    const float* __restrict__ te, const int* __restrict__ col,
    int* __restrict__ cursor, unsigned int* __restrict__ binned, int E) {
  const int lane = threadIdx.x & 63;
  const int gw = (blockIdx.x * 256 + threadIdx.x) >> 6;
  const int nw = (gridDim.x * 256) >> 6;
  for (int base = gw * 4; base < E; base += nw * 4) {
    int ne = E - base; if (ne > 4) ne = 4;
    int mypos = 0;
    if (lane < ne) {
      const int c = col[base + lane];
      mypos = atomicAdd(&cursor[c], 1);
    }
#pragma unroll
    for (int j = 0; j < 4; ++j) {
      if (j < ne) {
        const int pos = __builtin_amdgcn_readlane(mypos, j);
        const float lo = te[(size_t)(base + j) * IN_CH + lane];
        const float hi = te[(size_t)(base + j) * IN_CH + lane + 64];
        binned[(size_t)pos * 64 + lane] =
            (unsigned int)f2bf(lo) | ((unsigned int)f2bf(hi) << 16);
      }
    }
  }
}

// Block = 16 nodes; wave owns 4 nodes. Per node: sequential register-accumulate
// over its contiguous bf16 rows (16 rows in flight: half-wave x uint2), one
// plain LDS write per node (no atomics anywhere), then fused MFMA projection.
// C/D layout: col=lane&15, row=(lane>>4)*4+reg  [HW-verified]
__global__ __launch_bounds__(256) void phase2_kernel(
    const unsigned int* __restrict__ binned, const int* __restrict__ start,
    const int* __restrict__ cend, const unsigned short* __restrict__ Bpack,
    const float* __restrict__ bias, float* __restrict__ out, int N) {
  __shared__ float agg[16][AGG_STRIDE];
  const int tid = threadIdx.x;
  const int wave = tid >> 6;
  const int lane = tid & 63;
  const int half = lane >> 5;
  const int li   = lane & 31;
  const int m0 = blockIdx.x * 16;

#pragma unroll
  for (int q = 0; q < 4; ++q) {
    const int g = wave * 4 + q;          // local node slot 0..15
    const int n = m0 + g;
    float s00 = 0.f, s01 = 0.f, s10 = 0.f, s11 = 0.f;
    if (n < N) {
      const int s0 = start[n];
      const int e0 = cend[n];
      for (int r0 = s0; r0 < e0; r0 += 16) {
        const int rem = e0 - r0;         // wave-uniform
        uint2 v[8];
#pragma unroll
        for (int j = 0; j < 8; ++j) {
          int row = r0 + 2 * j + half;
          row = (row < e0) ? row : (e0 - 1);
          v[j] = *(const uint2*)(binned + (size_t)row * 64 + li * 2);
        }
#pragma unroll
        for (int j = 0; j < 8; ++j) {
          const float c = (2 * j + half < rem) ? 1.f : 0.f;
          s00 = fmaf(c, bflo2f(v[j].x), s00);
          s01 = fmaf(c, bfhi2f(v[j].x), s01);
          s10 = fmaf(c, bflo2f(v[j].y), s10);
          s11 = fmaf(c, bfhi2f(v[j].y), s11);
        }
      }
    }
    // combine halves: lane i += lane i+32
    s00 += __shfl_down(s00, 32);
    s01 += __shfl_down(s01, 32);
    s10 += __shfl_down(s10, 32);
    s11 += __shfl_down(s11, 32);
    if (half == 0) {
      // lane li holds channels 2li, 2li+1 (s00,s10) and 2li+64, 2li+65 (s01,s11)
      *(float2*)(&agg[g][2 * li])      = make_float2(s00, s10);
      *(float2*)(&agg[g][2 * li + 64]) = make_float2(s01, s11);
    }
  }
  __syncthreads();

  // ---- fused MFMA projection for nodes [m0, m0+16) ----
  const int r  = lane & 15;
  const int kb = lane >> 4;

  bf16x8 a[4];
#pragma unroll
  for (int ks = 0; ks < 4; ++ks) {
    bf16x8 t;
#pragma unroll
    for (int j = 0; j < 8; ++j) t[j] = (__bf16)agg[r][ks * 32 + kb * 8 + j];
    a[ks] = t;
  }

  f32x4 acc[4];
#pragma unroll
  for (int ct = 0; ct < 4; ++ct) acc[ct] = (f32x4){0.f, 0.f, 0.f, 0.f};

#pragma unroll
  for (int ct = 0; ct < 4; ++ct) {
    const int tn = wave * 4 + ct;
#pragma unroll
    for (int ks = 0; ks < 4; ++ks) {
      const bf16x8 bb = *(const bf16x8*)(Bpack + (size_t)((((tn * 4 + ks) * 4 + kb) * 16 + r) * 8));
      acc[ct] = __builtin_amdgcn_mfma_f32_16x16x32_bf16(a[ks], bb, acc[ct], 0, 0, 0);
    }
  }

#pragma unroll
  for (int ct = 0; ct < 4; ++ct) {
    const int colo = wave * 64 + ct * 16 + r;
    const float bv = bias[colo];
#pragma unroll
    for (int j = 0; j < 4; ++j) {
      const int m = m0 + kb * 4 + j;
      if (m < N) out[(size_t)m * OUT_CH + colo] = acc[ct][j] + bv;
    }
  }
}

extern "C" void kernel_launch(void* const* d_in, const int* in_sizes, int n_in,
                              void* d_out, int out_size, void* d_ws, size_t ws_size,
                              hipStream_t stream) {
  const int* edge_index = (const int*)d_in[0];
  const float* te       = (const float*)d_in[1];
  const float* W        = (const float*)d_in[3];
  const float* bias     = (const float*)d_in[4];
  float* out            = (float*)d_out;

  const int E = in_sizes[0] / 2;
  const int N = out_size / OUT_CH;
  const int* col = edge_index + E;  // edge_index[1]

  const int Np = (N + 3) & ~3;

  char* p = (char*)d_ws;
  unsigned short* Bpack = (unsigned short*)p;      p += 65536;
  int* cnt    = (int*)p;                           p += (size_t)Np * 4;
  int* start  = (int*)p;                           p += (size_t)Np * 4;
  int* cursor = (int*)p;                           p += (size_t)Np * 4;
  int* bsum   = (int*)p;                           p += 4096 * 4;
  p = (char*)(((uintptr_t)p + 255) & ~(uintptr_t)255);
  unsigned int* binned = (unsigned int*)p;         // E * 256B

  const int nb = (N + BLK_SCAN - 1) / BLK_SCAN;
  const int init_n = (N > IN_CH * OUT_CH) ? N : IN_CH * OUT_CH;
  const int K = (N + 15) / 16;

  hipLaunchKernelGGL(initB_kernel, dim3((init_n + 255) / 256), dim3(256), 0, stream,
                     W, Bpack, cnt, N);
  hipLaunchKernelGGL(hist_kernel, dim3((E / 4 + 255) / 256), dim3(256), 0, stream,
                     col, E, cnt);
  hipLaunchKernelGGL(scan_block_kernel, dim3(nb), dim3(BLK_SCAN), 0, stream,
                     cnt, N, start, bsum);
  hipLaunchKernelGGL(scan_bsum_kernel, dim3(1), dim3(256), 0, stream, bsum, nb);
  hipLaunchKernelGGL(add_offsets_kernel, dim3((N + 255) / 256), dim3(256), 0, stream,
                     start, bsum, cursor, N);
  hipLaunchKernelGGL(bin_kernel, dim3(2048), dim3(256), 0, stream,
                     te, col, cursor, binned, E);
  hipLaunchKernelGGL(phase2_kernel, dim3(K), dim3(256), 0, stream,
                     binned, start, cursor, Bpack, bias, out, N);
}

// Round 11
// 453.760 us; speedup vs baseline: 3.1626x; 1.0214x over previous
//
#include <hip/hip_runtime.h>
#include <hip/hip_bf16.h>

#define IN_CH 128
#define OUT_CH 256
#define BLK_SCAN 1024
#define AGG_STRIDE 132

typedef __bf16 bf16x8 __attribute__((ext_vector_type(8)));
typedef float f32x4 __attribute__((ext_vector_type(4)));

__device__ inline unsigned short f2bf(float f) {
  union { float f; unsigned int u; } v; v.f = f;
  unsigned int u = v.u;
  u += 0x7FFFu + ((u >> 16) & 1u);   // round-to-nearest-even
  return (unsigned short)(u >> 16);
}

__device__ inline float bfhi2f(unsigned int u) {
  union { unsigned int u; float f; } v; v.u = u & 0xFFFF0000u; return v.f;
}
__device__ inline float bflo2f(unsigned int u) {
  union { unsigned int u; float f; } v; v.u = u << 16; return v.f;
}

// Bpack element layout (ushort): idx = (((tn*4+ks)*4+kb)*16 + c)*8 + j
//   value = bf16( W[tn*16+c][ks*32 + kb*8 + j] )
// Same (kb,j)->k convention as A-fragments -> k-permutation cancels.
__global__ void initB_kernel(const float* __restrict__ W, unsigned short* __restrict__ Bpack,
                             int* __restrict__ cnt, int nzero) {
  int i = blockIdx.x * blockDim.x + threadIdx.x;
  if (i < nzero) cnt[i] = 0;
  if (i < IN_CH * OUT_CH) {
    const int j  = i & 7;
    const int c  = (i >> 3) & 15;
    const int kb = (i >> 7) & 3;
    const int ks = (i >> 9) & 3;
    const int tn = i >> 11;
    Bpack[i] = f2bf(W[(size_t)(tn * 16 + c) * IN_CH + ks * 32 + kb * 8 + j]);
  }
}

__global__ void hist_kernel(const int* __restrict__ col, int E, int* __restrict__ count) {
  int i = blockIdx.x * blockDim.x + threadIdx.x;
  int b = i * 4;
  if (b + 4 <= E) {
    const int4 c = *(const int4*)(col + b);
    atomicAdd(&count[c.x], 1);
    atomicAdd(&count[c.y], 1);
    atomicAdd(&count[c.z], 1);
    atomicAdd(&count[c.w], 1);
  } else {
    for (int j = b; j < E; ++j) atomicAdd(&count[col[j]], 1);
  }
}

// ---------- scan kernels ----------
__global__ __launch_bounds__(BLK_SCAN) void scan_block_kernel(
    const int* __restrict__ count, int N, int* __restrict__ excl, int* __restrict__ bsum) {
  __shared__ int wsum[16];
  const int tid = threadIdx.x;
  const int i = blockIdx.x * BLK_SCAN + tid;
  const int v = (i < N) ? count[i] : 0;
  int x = v;
#pragma unroll
  for (int d = 1; d < 64; d <<= 1) {
    int t = __shfl_up(x, d, 64);
    if ((tid & 63) >= d) x += t;
  }
  if ((tid & 63) == 63) wsum[tid >> 6] = x;
  __syncthreads();
  if (tid < 16) {
    int s = wsum[tid];
#pragma unroll
    for (int d = 1; d < 16; d <<= 1) {
      int t = __shfl_up(s, d, 16);
      if (tid >= d) s += t;
    }
    wsum[tid] = s;
  }
  __syncthreads();
  const int w = tid >> 6;
  const int prefix = (w == 0) ? 0 : wsum[w - 1];
  if (i < N) excl[i] = prefix + x - v;
  if (tid == BLK_SCAN - 1) bsum[blockIdx.x] = prefix + x;
}

__global__ void scan_bsum_kernel(int* __restrict__ bsum, int nb) {
  __shared__ int tmp[256];
  const int tid = threadIdx.x;
  int run = 0;
  for (int s = 0; s < nb; s += 256) {
    int v = (s + tid < nb) ? bsum[s + tid] : 0;
    tmp[tid] = v;
    __syncthreads();
    for (int d = 1; d < 256; d <<= 1) {
      int t = (tid >= d) ? tmp[tid - d] : 0;
      __syncthreads();
      tmp[tid] += t;
      __syncthreads();
    }
    if (s + tid < nb) bsum[s + tid] = run + tmp[tid] - v;
    run += tmp[255];
    __syncthreads();
  }
}

__global__ void add_offsets_kernel(int* __restrict__ excl, const int* __restrict__ bsum,
                                   int* __restrict__ cursor, int N) {
  int i = blockIdx.x * blockDim.x + threadIdx.x;
  if (i < N) {
    int o = excl[i] + bsum[i / BLK_SCAN];
    excl[i] = o;
    cursor[i] = o;
  }
}

// Stream te in edge order -> write bf16 rows (256B) into per-node slots.
// 8 rows per wave-iteration; one float2 load per lane per row (512B row in
// one dwordx2 instruction). Pack: uint l = channels (2l, 2l+1).
__global__ __launch_bounds__(256) void bin_kernel(
    const float* __restrict__ te, const int* __restrict__ col,
    int* __restrict__ cursor, unsigned int* __restrict__ binned, int E) {
  const int lane = threadIdx.x & 63;
  const int gw = (blockIdx.x * 256 + threadIdx.x) >> 6;
  const int nw = (gridDim.x * 256) >> 6;
  for (int base = gw * 8; base < E; base += nw * 8) {
    int ne = E - base; if (ne > 8) ne = 8;
    int mypos = 0;
    if (lane < ne) {
      mypos = atomicAdd(&cursor[col[base + lane]], 1);
    }
#pragma unroll
    for (int j = 0; j < 8; ++j) {
      if (j < ne) {
        const int pos = __builtin_amdgcn_readlane(mypos, j);
        const float2 v = *(const float2*)(te + (size_t)(base + j) * IN_CH + lane * 2);
        binned[(size_t)pos * 64 + lane] =
            (unsigned int)f2bf(v.x) | ((unsigned int)f2bf(v.y) << 16);
      }
    }
  }
}

// Block = 16 nodes; wave owns 4. Batch-0 loads of ALL 4 nodes hoisted (32
// uint2 in flight per wave), register accumulation, one float4 LDS write per
// node, then fused MFMA projection.
// C/D layout: col=lane&15, row=(lane>>4)*4+reg  [HW-verified]
__global__ __launch_bounds__(256) void phase2_kernel(
    const unsigned int* __restrict__ binned, const int* __restrict__ start,
    const int* __restrict__ cend, const unsigned short* __restrict__ Bpack,
    const float* __restrict__ bias, float* __restrict__ out, int N) {
  __shared__ float agg[16][AGG_STRIDE];
  const int tid = threadIdx.x;
  const int wave = tid >> 6;
  const int lane = tid & 63;
  const int half = lane >> 5;
  const int li   = lane & 31;
  const int m0 = blockIdx.x * 16;

  int s0[4], e0[4];
  float acc[4][4];
  uint2 v[4][8];
#pragma unroll
  for (int q = 0; q < 4; ++q) {
    const int n = m0 + wave * 4 + q;
    s0[q] = (n < N) ? start[n] : 0;
    e0[q] = (n < N) ? cend[n] : 0;
#pragma unroll
    for (int c = 0; c < 4; ++c) acc[q][c] = 0.f;
  }
  // batch 0 for all 4 nodes: 32 loads in flight
#pragma unroll
  for (int q = 0; q < 4; ++q) {
#pragma unroll
    for (int j = 0; j < 8; ++j) {
      int row = s0[q] + 2 * j + half;
      row = (row < e0[q]) ? row : (e0[q] > s0[q] ? e0[q] - 1 : 0);
      v[q][j] = *(const uint2*)(binned + (size_t)row * 64 + li * 2);
    }
  }
#pragma unroll
  for (int q = 0; q < 4; ++q) {
    const int rem = e0[q] - s0[q];
#pragma unroll
    for (int j = 0; j < 8; ++j) {
      const float c = (2 * j + half < rem) ? 1.f : 0.f;
      acc[q][0] = fmaf(c, bflo2f(v[q][j].x), acc[q][0]);
      acc[q][1] = fmaf(c, bfhi2f(v[q][j].x), acc[q][1]);
      acc[q][2] = fmaf(c, bflo2f(v[q][j].y), acc[q][2]);
      acc[q][3] = fmaf(c, bfhi2f(v[q][j].y), acc[q][3]);
    }
    // remaining batches (degree > 16: rarer path)
    for (int r0 = s0[q] + 16; r0 < e0[q]; r0 += 16) {
      const int rem2 = e0[q] - r0;
      uint2 w[8];
#pragma unroll
      for (int j = 0; j < 8; ++j) {
        int row = r0 + 2 * j + half;
        row = (row < e0[q]) ? row : (e0[q] - 1);
        w[j] = *(const uint2*)(binned + (size_t)row * 64 + li * 2);
      }
#pragma unroll
      for (int j = 0; j < 8; ++j) {
        const float c = (2 * j + half < rem2) ? 1.f : 0.f;
        acc[q][0] = fmaf(c, bflo2f(w[j].x), acc[q][0]);
        acc[q][1] = fmaf(c, bfhi2f(w[j].x), acc[q][1]);
        acc[q][2] = fmaf(c, bflo2f(w[j].y), acc[q][2]);
        acc[q][3] = fmaf(c, bfhi2f(w[j].y), acc[q][3]);
      }
    }
    acc[q][0] += __shfl_down(acc[q][0], 32);
    acc[q][1] += __shfl_down(acc[q][1], 32);
    acc[q][2] += __shfl_down(acc[q][2], 32);
    acc[q][3] += __shfl_down(acc[q][3], 32);
    if (half == 0) {
      // lane li holds channels 4li..4li+3 of node slot wave*4+q
      *(float4*)(&agg[wave * 4 + q][4 * li]) =
          make_float4(acc[q][0], acc[q][1], acc[q][2], acc[q][3]);
    }
  }
  __syncthreads();

  // ---- fused MFMA projection for nodes [m0, m0+16) ----
  const int r  = lane & 15;
  const int kb = lane >> 4;

  bf16x8 a[4];
#pragma unroll
  for (int ks = 0; ks < 4; ++ks) {
    bf16x8 t;
#pragma unroll
    for (int j = 0; j < 8; ++j) t[j] = (__bf16)agg[r][ks * 32 + kb * 8 + j];
    a[ks] = t;
  }

  f32x4 accm[4];
#pragma unroll
  for (int ct = 0; ct < 4; ++ct) accm[ct] = (f32x4){0.f, 0.f, 0.f, 0.f};

#pragma unroll
  for (int ct = 0; ct < 4; ++ct) {
    const int tn = wave * 4 + ct;
#pragma unroll
    for (int ks = 0; ks < 4; ++ks) {
      const bf16x8 bb = *(const bf16x8*)(Bpack + (size_t)((((tn * 4 + ks) * 4 + kb) * 16 + r) * 8));
      accm[ct] = __builtin_amdgcn_mfma_f32_16x16x32_bf16(a[ks], bb, accm[ct], 0, 0, 0);
    }
  }

#pragma unroll
  for (int ct = 0; ct < 4; ++ct) {
    const int colo = wave * 64 + ct * 16 + r;
    const float bv = bias[colo];
#pragma unroll
    for (int j = 0; j < 4; ++j) {
      const int m = m0 + kb * 4 + j;
      if (m < N) out[(size_t)m * OUT_CH + colo] = accm[ct][j] + bv;
    }
  }
}

extern "C" void kernel_launch(void* const* d_in, const int* in_sizes, int n_in,
                              void* d_out, int out_size, void* d_ws, size_t ws_size,
                              hipStream_t stream) {
  const int* edge_index = (const int*)d_in[0];
  const float* te       = (const float*)d_in[1];
  const float* W        = (const float*)d_in[3];
  const float* bias     = (const float*)d_in[4];
  float* out            = (float*)d_out;

  const int E = in_sizes[0] / 2;
  const int N = out_size / OUT_CH;
  const int* col = edge_index + E;  // edge_index[1]

  const int Np = (N + 3) & ~3;

  char* p = (char*)d_ws;
  unsigned short* Bpack = (unsigned short*)p;      p += 65536;
  int* cnt    = (int*)p;                           p += (size_t)Np * 4;
  int* start  = (int*)p;                           p += (size_t)Np * 4;
  int* cursor = (int*)p;                           p += (size_t)Np * 4;
  int* bsum   = (int*)p;                           p += 4096 * 4;
  p = (char*)(((uintptr_t)p + 255) & ~(uintptr_t)255);
  unsigned int* binned = (unsigned int*)p;         // E * 256B

  const int nb = (N + BLK_SCAN - 1) / BLK_SCAN;
  const int init_n = (N > IN_CH * OUT_CH) ? N : IN_CH * OUT_CH;
  const int K = (N + 15) / 16;

  hipLaunchKernelGGL(initB_kernel, dim3((init_n + 255) / 256), dim3(256), 0, stream,
                     W, Bpack, cnt, N);
  hipLaunchKernelGGL(hist_kernel, dim3((E / 4 + 255) / 256), dim3(256), 0, stream,
                     col, E, cnt);
  hipLaunchKernelGGL(scan_block_kernel, dim3(nb), dim3(BLK_SCAN), 0, stream,
                     cnt, N, start, bsum);
  hipLaunchKernelGGL(scan_bsum_kernel, dim3(1), dim3(256), 0, stream, bsum, nb);
  hipLaunchKernelGGL(add_offsets_kernel, dim3((N + 255) / 256), dim3(256), 0, stream,
                     start, bsum, cursor, N);
  hipLaunchKernelGGL(bin_kernel, dim3(2048), dim3(256), 0, stream,
                     te, col, cursor, binned, E);
  hipLaunchKernelGGL(phase2_kernel, dim3(K), dim3(256), 0, stream,
                     binned, start, cursor, Bpack, bias, out, N);
}

// Round 12
// 453.493 us; speedup vs baseline: 3.1644x; 1.0006x over previous
//
#include <hip/hip_runtime.h>
#include <hip/hip_bf16.h>

#define IN_CH 128
#define OUT_CH 256
#define BLK_SCAN 1024
#define AGG_STRIDE 132

typedef __bf16 bf16x8 __attribute__((ext_vector_type(8)));
typedef float f32x4 __attribute__((ext_vector_type(4)));

__device__ inline unsigned short f2bf(float f) {
  union { float f; unsigned int u; } v; v.f = f;
  unsigned int u = v.u;
  u += 0x7FFFu + ((u >> 16) & 1u);   // round-to-nearest-even
  return (unsigned short)(u >> 16);
}

__device__ inline float bfhi2f(unsigned int u) {
  union { unsigned int u; float f; } v; v.u = u & 0xFFFF0000u; return v.f;
}
__device__ inline float bflo2f(unsigned int u) {
  union { unsigned int u; float f; } v; v.u = u << 16; return v.f;
}

// Bpack element layout (ushort): idx = (((tn*4+ks)*4+kb)*16 + c)*8 + j
//   value = bf16( W[tn*16+c][ks*32 + kb*8 + j] )
// Same (kb,j)->k convention as A-fragments -> k-permutation cancels.
__global__ void initB_kernel(const float* __restrict__ W, unsigned short* __restrict__ Bpack,
                             int* __restrict__ cnt, int nzero) {
  int i = blockIdx.x * blockDim.x + threadIdx.x;
  if (i < nzero) cnt[i] = 0;
  if (i < IN_CH * OUT_CH) {
    const int j  = i & 7;
    const int c  = (i >> 3) & 15;
    const int kb = (i >> 7) & 3;
    const int ks = (i >> 9) & 3;
    const int tn = i >> 11;
    Bpack[i] = f2bf(W[(size_t)(tn * 16 + c) * IN_CH + ks * 32 + kb * 8 + j]);
  }
}

__global__ void hist_kernel(const int* __restrict__ col, int E, int* __restrict__ count) {
  int i = blockIdx.x * blockDim.x + threadIdx.x;
  int b = i * 4;
  if (b + 4 <= E) {
    const int4 c = *(const int4*)(col + b);
    atomicAdd(&count[c.x], 1);
    atomicAdd(&count[c.y], 1);
    atomicAdd(&count[c.z], 1);
    atomicAdd(&count[c.w], 1);
  } else {
    for (int j = b; j < E; ++j) atomicAdd(&count[col[j]], 1);
  }
}

// ---------- scan kernels ----------
__global__ __launch_bounds__(BLK_SCAN) void scan_block_kernel(
    const int* __restrict__ count, int N, int* __restrict__ excl, int* __restrict__ bsum) {
  __shared__ int wsum[16];
  const int tid = threadIdx.x;
  const int i = blockIdx.x * BLK_SCAN + tid;
  const int v = (i < N) ? count[i] : 0;
  int x = v;
#pragma unroll
  for (int d = 1; d < 64; d <<= 1) {
    int t = __shfl_up(x, d, 64);
    if ((tid & 63) >= d) x += t;
  }
  if ((tid & 63) == 63) wsum[tid >> 6] = x;
  __syncthreads();
  if (tid < 16) {
    int s = wsum[tid];
#pragma unroll
    for (int d = 1; d < 16; d <<= 1) {
      int t = __shfl_up(s, d, 16);
      if (tid >= d) s += t;
    }
    wsum[tid] = s;
  }
  __syncthreads();
  const int w = tid >> 6;
  const int prefix = (w == 0) ? 0 : wsum[w - 1];
  if (i < N) excl[i] = prefix + x - v;
  if (tid == BLK_SCAN - 1) bsum[blockIdx.x] = prefix + x;
}

__global__ void scan_bsum_kernel(int* __restrict__ bsum, int nb) {
  __shared__ int tmp[256];
  const int tid = threadIdx.x;
  int run = 0;
  for (int s = 0; s < nb; s += 256) {
    int v = (s + tid < nb) ? bsum[s + tid] : 0;
    tmp[tid] = v;
    __syncthreads();
    for (int d = 1; d < 256; d <<= 1) {
      int t = (tid >= d) ? tmp[tid - d] : 0;
      __syncthreads();
      tmp[tid] += t;
      __syncthreads();
    }
    if (s + tid < nb) bsum[s + tid] = run + tmp[tid] - v;
    run += tmp[255];
    __syncthreads();
  }
}

__global__ void add_offsets_kernel(int* __restrict__ excl, const int* __restrict__ bsum,
                                   int* __restrict__ cursor, int N) {
  int i = blockIdx.x * blockDim.x + threadIdx.x;
  if (i < N) {
    int o = excl[i] + bsum[i / BLK_SCAN];
    excl[i] = o;
    cursor[i] = o;
  }
}

// Stream te in edge order -> write bf16 rows (256B) into per-node slots.
// 8 rows per wave-iteration; one float2 load per lane per row (512B row in
// one dwordx2 instruction). Pack: uint l = channels (2l, 2l+1).
__global__ __launch_bounds__(256) void bin_kernel(
    const float* __restrict__ te, const int* __restrict__ col,
    int* __restrict__ cursor, unsigned int* __restrict__ binned, int E) {
  const int lane = threadIdx.x & 63;
  const int gw = (blockIdx.x * 256 + threadIdx.x) >> 6;
  const int nw = (gridDim.x * 256) >> 6;
  for (int base = gw * 8; base < E; base += nw * 8) {
    int ne = E - base; if (ne > 8) ne = 8;
    int mypos = 0;
    if (lane < ne) {
      mypos = atomicAdd(&cursor[col[base + lane]], 1);
    }
#pragma unroll
    for (int j = 0; j < 8; ++j) {
      if (j < ne) {
        const int pos = __builtin_amdgcn_readlane(mypos, j);
        const float2 v = *(const float2*)(te + (size_t)(base + j) * IN_CH + lane * 2);
        binned[(size_t)pos * 64 + lane] =
            (unsigned int)f2bf(v.x) | ((unsigned int)f2bf(v.y) << 16);
      }
    }
  }
}

// Block = 16 nodes; wave owns 4. Batch-0 loads of ALL 4 nodes hoisted (32
// uint2 in flight per wave), register accumulation, one float4 LDS write per
// node, then fused MFMA projection.
// C/D layout: col=lane&15, row=(lane>>4)*4+reg  [HW-verified]
__global__ __launch_bounds__(256) void phase2_kernel(
    const unsigned int* __restrict__ binned, const int* __restrict__ start,
    const int* __restrict__ cend, const unsigned short* __restrict__ Bpack,
    const float* __restrict__ bias, float* __restrict__ out, int N) {
  __shared__ float agg[16][AGG_STRIDE];
  const int tid = threadIdx.x;
  const int wave = tid >> 6;
  const int lane = tid & 63;
  const int half = lane >> 5;
  const int li   = lane & 31;
  const int m0 = blockIdx.x * 16;

  int s0[4], e0[4];
  float acc[4][4];
  uint2 v[4][8];
#pragma unroll
  for (int q = 0; q < 4; ++q) {
    const int n = m0 + wave * 4 + q;
    s0[q] = (n < N) ? start[n] : 0;
    e0[q] = (n < N) ? cend[n] : 0;
#pragma unroll
    for (int c = 0; c < 4; ++c) acc[q][c] = 0.f;
  }
  // batch 0 for all 4 nodes: 32 loads in flight
#pragma unroll
  for (int q = 0; q < 4; ++q) {
#pragma unroll
    for (int j = 0; j < 8; ++j) {
      int row = s0[q] + 2 * j + half;
      row = (row < e0[q]) ? row : (e0[q] > s0[q] ? e0[q] - 1 : 0);
      v[q][j] = *(const uint2*)(binned + (size_t)row * 64 + li * 2);
    }
  }
#pragma unroll
  for (int q = 0; q < 4; ++q) {
    const int rem = e0[q] - s0[q];
#pragma unroll
    for (int j = 0; j < 8; ++j) {
      const float c = (2 * j + half < rem) ? 1.f : 0.f;
      acc[q][0] = fmaf(c, bflo2f(v[q][j].x), acc[q][0]);
      acc[q][1] = fmaf(c, bfhi2f(v[q][j].x), acc[q][1]);
      acc[q][2] = fmaf(c, bflo2f(v[q][j].y), acc[q][2]);
      acc[q][3] = fmaf(c, bfhi2f(v[q][j].y), acc[q][3]);
    }
    // remaining batches (degree > 16: rarer path)
    for (int r0 = s0[q] + 16; r0 < e0[q]; r0 += 16) {
      const int rem2 = e0[q] - r0;
      uint2 w[8];
#pragma unroll
      for (int j = 0; j < 8; ++j) {
        int row = r0 + 2 * j + half;
        row = (row < e0[q]) ? row : (e0[q] - 1);
        w[j] = *(const uint2*)(binned + (size_t)row * 64 + li * 2);
      }
#pragma unroll
      for (int j = 0; j < 8; ++j) {
        const float c = (2 * j + half < rem2) ? 1.f : 0.f;
        acc[q][0] = fmaf(c, bflo2f(w[j].x), acc[q][0]);
        acc[q][1] = fmaf(c, bfhi2f(w[j].x), acc[q][1]);
        acc[q][2] = fmaf(c, bflo2f(w[j].y), acc[q][2]);
        acc[q][3] = fmaf(c, bfhi2f(w[j].y), acc[q][3]);
      }
    }
    acc[q][0] += __shfl_down(acc[q][0], 32);
    acc[q][1] += __shfl_down(acc[q][1], 32);
    acc[q][2] += __shfl_down(acc[q][2], 32);
    acc[q][3] += __shfl_down(acc[q][3], 32);
    if (half == 0) {
      // lane li holds channels 4li..4li+3 of node slot wave*4+q
      *(float4*)(&agg[wave * 4 + q][4 * li]) =
          make_float4(acc[q][0], acc[q][1], acc[q][2], acc[q][3]);
    }
  }
  __syncthreads();

  // ---- fused MFMA projection for nodes [m0, m0+16) ----
  const int r  = lane & 15;
  const int kb = lane >> 4;

  bf16x8 a[4];
#pragma unroll
  for (int ks = 0; ks < 4; ++ks) {
    bf16x8 t;
#pragma unroll
    for (int j = 0; j < 8; ++j) t[j] = (__bf16)agg[r][ks * 32 + kb * 8 + j];
    a[ks] = t;
  }

  f32x4 accm[4];
#pragma unroll
  for (int ct = 0; ct < 4; ++ct) accm[ct] = (f32x4){0.f, 0.f, 0.f, 0.f};

#pragma unroll
  for (int ct = 0; ct < 4; ++ct) {
    const int tn = wave * 4 + ct;
#pragma unroll
    for (int ks = 0; ks < 4; ++ks) {
      const bf16x8 bb = *(const bf16x8*)(Bpack + (size_t)((((tn * 4 + ks) * 4 + kb) * 16 + r) * 8));
      accm[ct] = __builtin_amdgcn_mfma_f32_16x16x32_bf16(a[ks], bb, accm[ct], 0, 0, 0);
    }
  }

#pragma unroll
  for (int ct = 0; ct < 4; ++ct) {
    const int colo = wave * 64 + ct * 16 + r;
    const float bv = bias[colo];
#pragma unroll
    for (int j = 0; j < 4; ++j) {
      const int m = m0 + kb * 4 + j;
      if (m < N) out[(size_t)m * OUT_CH + colo] = accm[ct][j] + bv;
    }
  }
}

extern "C" void kernel_launch(void* const* d_in, const int* in_sizes, int n_in,
                              void* d_out, int out_size, void* d_ws, size_t ws_size,
                              hipStream_t stream) {
  const int* edge_index = (const int*)d_in[0];
  const float* te       = (const float*)d_in[1];
  const float* W        = (const float*)d_in[3];
  const float* bias     = (const float*)d_in[4];
  float* out            = (float*)d_out;

  const int E = in_sizes[0] / 2;
  const int N = out_size / OUT_CH;
  const int* col = edge_index + E;  // edge_index[1]

  const int Np = (N + 3) & ~3;

  char* p = (char*)d_ws;
  unsigned short* Bpack = (unsigned short*)p;      p += 65536;
  int* cnt    = (int*)p;                           p += (size_t)Np * 4;
  int* start  = (int*)p;                           p += (size_t)Np * 4;
  int* cursor = (int*)p;                           p += (size_t)Np * 4;
  int* bsum   = (int*)p;                           p += 4096 * 4;
  p = (char*)(((uintptr_t)p + 255) & ~(uintptr_t)255);
  unsigned int* binned = (unsigned int*)p;         // E * 256B

  const int nb = (N + BLK_SCAN - 1) / BLK_SCAN;
  const int init_n = (N > IN_CH * OUT_CH) ? N : IN_CH * OUT_CH;
  const int K = (N + 15) / 16;

  hipLaunchKernelGGL(initB_kernel, dim3((init_n + 255) / 256), dim3(256), 0, stream,
                     W, Bpack, cnt, N);
  hipLaunchKernelGGL(hist_kernel, dim3((E / 4 + 255) / 256), dim3(256), 0, stream,
                     col, E, cnt);
  hipLaunchKernelGGL(scan_block_kernel, dim3(nb), dim3(BLK_SCAN), 0, stream,
                     cnt, N, start, bsum);
  hipLaunchKernelGGL(scan_bsum_kernel, dim3(1), dim3(256), 0, stream, bsum, nb);
  hipLaunchKernelGGL(add_offsets_kernel, dim3((N + 255) / 256), dim3(256), 0, stream,
                     start, bsum, cursor, N);
  hipLaunchKernelGGL(bin_kernel, dim3(2048), dim3(256), 0, stream,
                     te, col, cursor, binned, E);
  hipLaunchKernelGGL(phase2_kernel, dim3(K), dim3(256), 0, stream,
                     binned, start, cursor, Bpack, bias, out, N);
}